// Round 1
// baseline (1589.667 us; speedup 1.0000x reference)
//
#include <hip/hip_runtime.h>
#include <stdint.h>

// ---- problem constants ----
#define B_N   2
#define HQ_N  32
#define HKV_N 8
#define QL_N  1024
#define SL_N  4096
#define DH_N  128
#define ROPE_N 64
#define RANK_N 512
#define DEFF_N 576   // RANK + ROPE

typedef _Float16 f16;
typedef _Float16 half8 __attribute__((ext_vector_type(8)));
typedef float floatx16 __attribute__((ext_vector_type(16)));

union H8 { half8 h; uint64_t q[2]; };
union H4 { f16 h[4]; uint64_t q; };

// ---------------------------------------------------------------------------
// prep 1: fp32 -> fp16 convert of C_kv_t2 and K_rope_t2
// ---------------------------------------------------------------------------
__global__ __launch_bounds__(256) void k_convert(const float* __restrict__ C,
                                                 const float* __restrict__ Kr,
                                                 f16* __restrict__ Cf,
                                                 f16* __restrict__ Krf) {
  const size_t NC = (size_t)B_N * SL_N * RANK_N;            // 4194304
  size_t idx = ((size_t)blockIdx.x * 256 + threadIdx.x) * 8; // covers 8388608
  const float* src;
  f16* dst;
  if (idx < NC) { src = C + idx;        dst = Cf + idx; }
  else          { src = Kr + (idx - NC); dst = Krf + (idx - NC); }
  float4 a = *(const float4*)(src);
  float4 b = *(const float4*)(src + 4);
  H8 o;
  o.h[0] = (f16)a.x; o.h[1] = (f16)a.y; o.h[2] = (f16)a.z; o.h[3] = (f16)a.w;
  o.h[4] = (f16)b.x; o.h[5] = (f16)b.y; o.h[6] = (f16)b.z; o.h[7] = (f16)b.w;
  *(half8*)dst = o.h;
}

// ---------------------------------------------------------------------------
// prep 2: CW^T[b][c][s] = (C[b] @ W_UV)^T   in fp16.   grid = 2*64 blocks.
// block = (b, s-chunk of 64)
// ---------------------------------------------------------------------------
__global__ __launch_bounds__(256) void k_cw(const float* __restrict__ C,
                                            const float* __restrict__ WUV,
                                            f16* __restrict__ CWT) {
  __shared__ f16 Wc[256 * 128];   // r-chunk x c
  __shared__ f16 Cc[64 * 264];    // s x r-chunk (pad 264)
  __shared__ f16 cwl[64 * 136];   // s x c (pad 136)
  int t = threadIdx.x;
  int b = blockIdx.x >> 6, sc = blockIdx.x & 63;
  int s0 = sc * 64;
  int sl = t >> 2, cq = t & 3;    // thread owns (s=sl, c = cq*32..+31)
  float acc[32];
#pragma unroll
  for (int i = 0; i < 32; i++) acc[i] = 0.f;
  for (int rc = 0; rc < 2; ++rc) {
    __syncthreads();
    for (int i = 0; i < 128; i++) {  // stage W_UV rows rc*256..+255
      int flat = i * 256 + t;
      Wc[flat] = (f16)WUV[(size_t)rc * 256 * 128 + flat];
    }
    for (int i = 0; i < 64; i++) {   // stage C[s0..+63][rc*256..+255]
      int flat = i * 256 + t; int s = flat >> 8, r = flat & 255;
      Cc[s * 264 + r] = (f16)C[((size_t)b * SL_N + s0 + s) * RANK_N + rc * 256 + r];
    }
    __syncthreads();
    for (int r = 0; r < 256; ++r) {
      float a = (float)Cc[sl * 264 + r];
#pragma unroll
      for (int u = 0; u < 4; u++) {
        half8 w = *(const half8*)(Wc + r * 128 + cq * 32 + u * 8);
#pragma unroll
        for (int j = 0; j < 8; j++) acc[u * 8 + j] += a * (float)w[j];
      }
    }
  }
  __syncthreads();
#pragma unroll
  for (int i = 0; i < 32; i++) cwl[sl * 136 + cq * 32 + i] = (f16)acc[i];
  __syncthreads();
#pragma unroll
  for (int i = 0; i < 4; i++) {   // write CWT[b][c][s0+..] coalesced
    int flat = i * 256 + t; int c = flat >> 3, ch = flat & 7;
    H8 o;
#pragma unroll
    for (int j = 0; j < 8; j++) o.h[j] = cwl[(ch * 8 + j) * 136 + c];
    *(half8*)(CWT + ((size_t)b * DH_N + c) * SL_N + s0 + ch * 8) = o.h;
  }
}

// ---------------------------------------------------------------------------
// prep 3: Q_eff[b][h][q][0:512]=Q_abs, [512:576]=Q_rope, fp16.
// grid = 2*32*4 blocks, block handles 256 q rows.
// ---------------------------------------------------------------------------
__global__ __launch_bounds__(256) void k_prepq(const float* __restrict__ Q,
                                               const float* __restrict__ Ul,
                                               const float* __restrict__ WUK,
                                               f16* __restrict__ Qeff) {
  __shared__ f16  Wl[64 * 512];     // W_UK fp16
  __shared__ float Us[64 * 65];     // U_l padded
  __shared__ float qt[16 * 128];
  __shared__ float rt[16 * 129];
  int t = threadIdx.x;
  int qc = blockIdx.x & 3; int h = (blockIdx.x >> 2) & 31; int b = blockIdx.x >> 7;
#pragma unroll
  for (int i = 0; i < 16; i++) { int flat = i * 256 + t; int j = flat >> 6, ii = flat & 63;
    Us[j * 65 + ii] = Ul[j * 64 + ii]; }
  for (int i = 0; i < 128; i++) { int flat = i * 256 + t; Wl[flat] = (f16)WUK[flat]; }
  __syncthreads();
  int r16 = t >> 4, lo = t & 15;
  for (int g = 0; g < 16; ++g) {
    int q0 = qc * 256 + g * 16;
    size_t rowbase = (size_t)(b * HQ_N + h) * QL_N + q0;
#pragma unroll
    for (int i = 0; i < 8; i++) { int flat = i * 256 + t; int r = flat >> 7, d = flat & 127;
      qt[r * 128 + d] = Q[(rowbase + r) * DH_N + d]; }
    __syncthreads();
    {  // Q_rot: thread (r16, j = lo*8..+7)
      float acc[8];
#pragma unroll
      for (int u = 0; u < 8; u++) acc[u] = 0.f;
      int jbase = lo * 8;
      int src = (jbase >= 64) ? 64 : 0; int jj = jbase & 63;
      for (int i = 0; i < 64; ++i) {
        float a = qt[r16 * 128 + src + i];
#pragma unroll
        for (int u = 0; u < 8; u++) acc[u] += a * Us[(jj + u) * 65 + i];
      }
#pragma unroll
      for (int u = 0; u < 8; u++) rt[r16 * 129 + jbase + u] = acc[u];
    }
    __syncthreads();
#pragma unroll
    for (int u = 0; u < 4; u++) {  // Q_rope out
      int j = lo * 4 + u;
      Qeff[(rowbase + r16) * DEFF_N + 512 + j] = (f16)rt[r16 * 129 + j];
    }
    {  // Q_abs: thread (r16, c = lo*32..+31)
      float acc[32];
#pragma unroll
      for (int i = 0; i < 32; i++) acc[i] = 0.f;
      for (int j = 0; j < 64; ++j) {
        float a = rt[r16 * 129 + 64 + j];
#pragma unroll
        for (int u = 0; u < 4; u++) {
          half8 w = *(const half8*)(Wl + j * 512 + lo * 32 + u * 8);
#pragma unroll
          for (int j2 = 0; j2 < 8; j2++) acc[u * 8 + j2] += a * (float)w[j2];
        }
      }
      f16* dst = Qeff + (rowbase + r16) * DEFF_N + lo * 32;
#pragma unroll
      for (int u = 0; u < 4; u++) {
        H8 o;
#pragma unroll
        for (int j2 = 0; j2 < 8; j2++) o.h[j2] = (f16)acc[u * 8 + j2];
        *(half8*)(dst + u * 8) = o.h;
      }
    }
    __syncthreads();
  }
}

// ---------------------------------------------------------------------------
// flash kernel: S^T formulation, online softmax, PV against precomputed CW^T.
// grid = 512 = (b, h, q-tile of 128). 4 waves. s-tiles of 64. 32x32x16 f16 MFMA.
// ---------------------------------------------------------------------------
#define KST 588   // k_lds row stride (halfs): 2-way-conflict b64 reads
#define CST 76
#define PST 76

__global__ __launch_bounds__(256, 1) void k_flash(
    const f16* __restrict__ Qeff, const f16* __restrict__ Cf,
    const f16* __restrict__ Krf, const f16* __restrict__ CWT,
    float* __restrict__ out) {
  __shared__ __align__(16) char smem[64 * KST * 2 + 128 * CST * 2 + 128 * PST * 2];
  f16* k_lds   = (f16*)smem;                                    // [64][KST]  K_eff tile
  f16* cwt_lds = (f16*)(smem + 64 * KST * 2);                   // [128][CST] CW^T tile
  f16* p_lds   = (f16*)(smem + 64 * KST * 2 + 128 * CST * 2);   // [128][PST] P^T as [q][s]
  float* ot    = (float*)smem;                                  // epilogue [128][132]

  int t = threadIdx.x;
  int wave = t >> 6, lane = t & 63, l31 = lane & 31, lhi = lane >> 5;
  int qt = blockIdx.x & 7; int h = (blockIdx.x >> 3) & 31; int b = blockIdx.x >> 8;
  int kv = h >> 2;
  int qloc = wave * 32 + l31;

  // persistent Q fragments (B-operand): lane holds Q_eff[q = qbase+l31][kk*16+lhi*8 ..+7]
  half8 qf[36];
  {
    const f16* qrow = Qeff + ((size_t)(b * HQ_N + h) * QL_N + qt * 128 + qloc) * DEFF_N + lhi * 8;
#pragma unroll
    for (int kk = 0; kk < 36; kk++) qf[kk] = *(const half8*)(qrow + kk * 16);
  }

  floatx16 oacc[4];
#pragma unroll
  for (int ct = 0; ct < 4; ct++)
#pragma unroll
    for (int r = 0; r < 16; r++) oacc[ct][r] = 0.f;
  float m_run = -1e30f, l_run = 0.f;

  const f16* Cb = Cf + (size_t)b * SL_N * RANK_N;
  const f16* Kb = Krf + (size_t)(b * HKV_N + kv) * SL_N * ROPE_N;
  const f16* Wb = CWT + (size_t)b * DH_N * SL_N;

  for (int it = 0; it < 64; ++it) {
    int s0 = it * 64;
    __syncthreads();
    // ---- stage K_eff tile: C part (cols 0..511) ----
#pragma unroll
    for (int i = 0; i < 16; i++) {
      int flat = i * 256 + t; int s = flat >> 6, ch = flat & 63;
      H8 v; v.h = *(const half8*)(Cb + (size_t)(s0 + s) * RANK_N + ch * 8);
      uint64_t* d = (uint64_t*)(k_lds + s * KST + ch * 8);
      d[0] = v.q[0]; d[1] = v.q[1];
    }
    // ---- rope part (cols 512..575) ----
#pragma unroll
    for (int i = 0; i < 2; i++) {
      int flat = i * 256 + t; int s = flat >> 3, ch = flat & 7;
      H8 v; v.h = *(const half8*)(Kb + (size_t)(s0 + s) * ROPE_N + ch * 8);
      uint64_t* d = (uint64_t*)(k_lds + s * KST + 512 + ch * 8);
      d[0] = v.q[0]; d[1] = v.q[1];
    }
    // ---- CW^T tile ----
#pragma unroll
    for (int i = 0; i < 4; i++) {
      int flat = i * 256 + t; int c = flat >> 3, ch = flat & 7;
      H8 v; v.h = *(const half8*)(Wb + (size_t)c * SL_N + s0 + ch * 8);
      uint64_t* d = (uint64_t*)(cwt_lds + c * CST + ch * 8);
      d[0] = v.q[0]; d[1] = v.q[1];
    }
    __syncthreads();

    // ---- S^T = K_eff · Q^T : wave handles q-quarter `wave`, both s-halves ----
    floatx16 sa0, sa1;
#pragma unroll
    for (int r = 0; r < 16; r++) { sa0[r] = 0.f; sa1[r] = 0.f; }
    const f16* ka = k_lds + l31 * KST + lhi * 8;
#pragma unroll
    for (int kk = 0; kk < 36; kk++) {
      H8 a0, a1;
      const uint64_t* p0 = (const uint64_t*)(ka + kk * 16);
      a0.q[0] = p0[0]; a0.q[1] = p0[1];
      const uint64_t* p1 = (const uint64_t*)(ka + 32 * KST + kk * 16);
      a1.q[0] = p1[0]; a1.q[1] = p1[1];
      sa0 = __builtin_amdgcn_mfma_f32_32x32x16_f16(a0.h, qf[kk], sa0, 0, 0, 0);
      sa1 = __builtin_amdgcn_mfma_f32_32x32x16_f16(a1.h, qf[kk], sa1, 0, 0, 0);
    }

    // ---- online softmax: per-lane q, s lives in regs (+ partner lane via xor32) ----
    float mt = -1e30f;
#pragma unroll
    for (int r = 0; r < 16; r++) { mt = fmaxf(mt, sa0[r]); mt = fmaxf(mt, sa1[r]); }
    mt = fmaxf(mt, __shfl_xor(mt, 32, 64));
    float m_new = fmaxf(m_run, mt);
    float alpha = __expf(m_run - m_new);
    float p0v[16], p1v[16];
    float psum = 0.f;
#pragma unroll
    for (int r = 0; r < 16; r++) {
      p0v[r] = __expf(sa0[r] - m_new); psum += p0v[r];
      p1v[r] = __expf(sa1[r] - m_new); psum += p1v[r];
    }
    psum += __shfl_xor(psum, 32, 64);
    l_run = l_run * alpha + psum;
    m_run = m_new;
#pragma unroll
    for (int ct = 0; ct < 4; ct++)
#pragma unroll
      for (int r = 0; r < 16; r++) oacc[ct][r] *= alpha;

    // ---- write P^T as [q][s] (each wave writes/reads only its own q rows) ----
#pragma unroll
    for (int sh = 0; sh < 2; ++sh) {
#pragma unroll
      for (int g = 0; g < 4; ++g) {
        H4 w;
        const float* pv = sh ? p1v : p0v;
        w.h[0] = (f16)pv[g * 4 + 0]; w.h[1] = (f16)pv[g * 4 + 1];
        w.h[2] = (f16)pv[g * 4 + 2]; w.h[3] = (f16)pv[g * 4 + 3];
        *(uint64_t*)(p_lds + qloc * PST + sh * 32 + g * 8 + lhi * 4) = w.q;
      }
    }

    // ---- PV: out_t^T tile = CW^T (A) · P^T (B), K = s (64 = 4 ksteps) ----
#pragma unroll
    for (int ks = 0; ks < 4; ++ks) {
      H8 bf;
      const uint64_t* pb = (const uint64_t*)(p_lds + qloc * PST + ks * 16 + lhi * 8);
      bf.q[0] = pb[0]; bf.q[1] = pb[1];
#pragma unroll
      for (int ct = 0; ct < 4; ct++) {
        H8 af;
        const uint64_t* pa = (const uint64_t*)(cwt_lds + (ct * 32 + l31) * CST + ks * 16 + lhi * 8);
        af.q[0] = pa[0]; af.q[1] = pa[1];
        oacc[ct] = __builtin_amdgcn_mfma_f32_32x32x16_f16(af.h, bf.h, oacc[ct], 0, 0, 0);
      }
    }
  }

  __syncthreads();
  // ---- epilogue: divide by l, transpose via LDS, coalesced fp32 store ----
  float inv = 1.0f / l_run;
#pragma unroll
  for (int ct = 0; ct < 4; ct++)
#pragma unroll
    for (int r = 0; r < 16; r++) {
      int c = ct * 32 + (r & 3) + 8 * (r >> 2) + 4 * lhi;
      ot[qloc * 132 + c] = oacc[ct][r] * inv;
    }
  __syncthreads();
  float* outp = out + ((size_t)(b * HQ_N + h) * QL_N + qt * 128) * DH_N;
#pragma unroll
  for (int i = 0; i < 16; i++) {
    int flat = i * 256 + t; int q = flat >> 5, ch = flat & 31;
    float4 v;
    v.x = ot[q * 132 + ch * 4 + 0];
    v.y = ot[q * 132 + ch * 4 + 1];
    v.z = ot[q * 132 + ch * 4 + 2];
    v.w = ot[q * 132 + ch * 4 + 3];
    *(float4*)(outp + (size_t)q * DH_N + ch * 4) = v;
  }
}

// ---------------------------------------------------------------------------
extern "C" void kernel_launch(void* const* d_in, const int* in_sizes, int n_in,
                              void* d_out, int out_size, void* d_ws, size_t ws_size,
                              hipStream_t stream) {
  (void)in_sizes; (void)n_in; (void)out_size; (void)ws_size;
  const float* Q   = (const float*)d_in[0];
  const float* C   = (const float*)d_in[1];
  const float* Kr  = (const float*)d_in[2];
  const float* Ul  = (const float*)d_in[3];
  const float* WUK = (const float*)d_in[4];
  const float* WUV = (const float*)d_in[5];
  float* out = (float*)d_out;
  char* ws = (char*)d_ws;
  // workspace carve (needs ~94.4 MB)
  f16* Qeff = (f16*)ws;                   // 75497472 B
  f16* Cf   = (f16*)(ws + 75497472);      //  8388608 B
  f16* Krf  = (f16*)(ws + 83886080);      //  8388608 B
  f16* CWT  = (f16*)(ws + 92274688);      //  2097152 B

  hipLaunchKernelGGL(k_convert, dim3(4096), dim3(256), 0, stream, C, Kr, Cf, Krf);
  hipLaunchKernelGGL(k_cw,      dim3(128),  dim3(256), 0, stream, C, WUV, CWT);
  hipLaunchKernelGGL(k_prepq,   dim3(256),  dim3(256), 0, stream, Q, Ul, WUK, Qeff);
  hipLaunchKernelGGL(k_flash,   dim3(512),  dim3(256), 0, stream, Qeff, Cf, Krf, CWT, out);
}

// Round 2
// 983.486 us; speedup vs baseline: 1.6164x; 1.6164x over previous
//
#include <hip/hip_runtime.h>
#include <stdint.h>

// ---- problem constants ----
#define B_N   2
#define HQ_N  32
#define HKV_N 8
#define QL_N  1024
#define SL_N  4096
#define DH_N  128
#define ROPE_N 64
#define RANK_N 512
#define DEFF_N 576   // RANK + ROPE

typedef _Float16 f16;
typedef _Float16 half8 __attribute__((ext_vector_type(8)));
typedef float floatx16 __attribute__((ext_vector_type(16)));

union H8 { half8 h; uint64_t q[2]; };
union H4 { f16 h[4]; uint64_t q; };

// ---------------------------------------------------------------------------
// prep 1: fp32 -> fp16 convert of C_kv_t2 and K_rope_t2
// ---------------------------------------------------------------------------
__global__ __launch_bounds__(256) void k_convert(const float* __restrict__ C,
                                                 const float* __restrict__ Kr,
                                                 f16* __restrict__ Cf,
                                                 f16* __restrict__ Krf) {
  const size_t NC = (size_t)B_N * SL_N * RANK_N;            // 4194304
  size_t idx = ((size_t)blockIdx.x * 256 + threadIdx.x) * 8; // covers 8388608
  const float* src;
  f16* dst;
  if (idx < NC) { src = C + idx;        dst = Cf + idx; }
  else          { src = Kr + (idx - NC); dst = Krf + (idx - NC); }
  float4 a = *(const float4*)(src);
  float4 b = *(const float4*)(src + 4);
  H8 o;
  o.h[0] = (f16)a.x; o.h[1] = (f16)a.y; o.h[2] = (f16)a.z; o.h[3] = (f16)a.w;
  o.h[4] = (f16)b.x; o.h[5] = (f16)b.y; o.h[6] = (f16)b.z; o.h[7] = (f16)b.w;
  *(half8*)dst = o.h;
}

// ---------------------------------------------------------------------------
// prep 2: M2T[c][d] (576 x 128, f16): Q_eff = Q @ M2.
//   c<512  (nope/abs): M2T[c][64+i] = sum_j U_l[j][i] * W_UK[j][c], else 0
//   c>=512 (rope):     M2T[c][d]    = U_l[c-512][d] for d<64, else 0
// grid = 288 blocks x 256.
// ---------------------------------------------------------------------------
__global__ __launch_bounds__(256) void k_m2(const float* __restrict__ Ul,
                                            const float* __restrict__ WUK,
                                            f16* __restrict__ M2T) {
  int idx = blockIdx.x * 256 + threadIdx.x;   // < 73728
  int c = idx >> 7, d = idx & 127;
  float v = 0.f;
  if (c < 512) {
    if (d >= 64) {
      int i = d - 64;
      for (int j = 0; j < 64; ++j) v += Ul[j * 64 + i] * WUK[j * 512 + c];
    }
  } else {
    if (d < 64) v = Ul[(c - 512) * 64 + d];
  }
  M2T[idx] = (f16)v;
}

// ---------------------------------------------------------------------------
// prep 3: Qeff = f16(Q) @ M2  via MFMA.  M=65536, K=128, N=576.
// grid = 1536 = 512 m-tiles(128) x 3 n-tiles(192). 4 waves; wave w: 32 q rows.
// ---------------------------------------------------------------------------
__global__ __launch_bounds__(256) void k_qeff(const float* __restrict__ Q,
                                              const f16* __restrict__ M2T,
                                              f16* __restrict__ Qeff) {
  __shared__ __align__(16) f16 qs[128 * 132];
  int t = threadIdx.x;
  int wave = t >> 6, lane = t & 63, l31 = lane & 31, lhi = lane >> 5;
  int mb = blockIdx.x & 511, nb = blockIdx.x >> 9;
  size_t m0 = (size_t)mb * 128;
  int n0 = nb * 192;
  // stage Q tile (fp32 -> f16)
#pragma unroll
  for (int i = 0; i < 16; i++) {
    int flat = i * 256 + t; int row = flat >> 5, seg = flat & 31;
    float4 v = *(const float4*)(Q + (m0 + row) * DH_N + seg * 4);
    H4 o; o.h[0] = (f16)v.x; o.h[1] = (f16)v.y; o.h[2] = (f16)v.z; o.h[3] = (f16)v.w;
    *(uint64_t*)(qs + row * 132 + seg * 4) = o.q;
  }
  __syncthreads();
  floatx16 acc[6];
#pragma unroll
  for (int ct = 0; ct < 6; ct++)
#pragma unroll
    for (int r = 0; r < 16; r++) acc[ct][r] = 0.f;
#pragma unroll
  for (int kk = 0; kk < 8; ++kk) {
    H8 af;
    const uint64_t* pa = (const uint64_t*)(qs + (wave * 32 + l31) * 132 + kk * 16 + lhi * 8);
    af.q[0] = pa[0]; af.q[1] = pa[1];
#pragma unroll
    for (int ct = 0; ct < 6; ct++) {
      H8 bf; bf.h = *(const half8*)(M2T + (size_t)(n0 + ct * 32 + l31) * 128 + kk * 16 + lhi * 8);
      acc[ct] = __builtin_amdgcn_mfma_f32_32x32x16_f16(af.h, bf.h, acc[ct], 0, 0, 0);
    }
  }
#pragma unroll
  for (int ct = 0; ct < 6; ct++)
#pragma unroll
    for (int r = 0; r < 16; r++) {
      int row = (r & 3) + 8 * (r >> 2) + 4 * lhi;
      size_t q = m0 + wave * 32 + row;
      Qeff[q * DEFF_N + n0 + ct * 32 + l31] = (f16)acc[ct][r];
    }
}

// ---------------------------------------------------------------------------
// prep 4: CW^T[b][c][s] = (C[b] @ W_UV)^T   in fp16.   grid = 2*64 blocks.
// ---------------------------------------------------------------------------
__global__ __launch_bounds__(256) void k_cw(const float* __restrict__ C,
                                            const float* __restrict__ WUV,
                                            f16* __restrict__ CWT) {
  __shared__ f16 Wc[256 * 128];   // r-chunk x c
  __shared__ f16 Cc[64 * 264];    // s x r-chunk (pad 264)
  __shared__ f16 cwl[64 * 136];   // s x c (pad 136)
  int t = threadIdx.x;
  int b = blockIdx.x >> 6, sc = blockIdx.x & 63;
  int s0 = sc * 64;
  int sl = t >> 2, cq = t & 3;    // thread owns (s=sl, c = cq*32..+31)
  float acc[32];
#pragma unroll
  for (int i = 0; i < 32; i++) acc[i] = 0.f;
  for (int rc = 0; rc < 2; ++rc) {
    __syncthreads();
    for (int i = 0; i < 128; i++) {
      int flat = i * 256 + t;
      Wc[flat] = (f16)WUV[(size_t)rc * 256 * 128 + flat];
    }
    for (int i = 0; i < 64; i++) {
      int flat = i * 256 + t; int s = flat >> 8, r = flat & 255;
      Cc[s * 264 + r] = (f16)C[((size_t)b * SL_N + s0 + s) * RANK_N + rc * 256 + r];
    }
    __syncthreads();
    for (int r = 0; r < 256; ++r) {
      float a = (float)Cc[sl * 264 + r];
#pragma unroll
      for (int u = 0; u < 4; u++) {
        half8 w = *(const half8*)(Wc + r * 128 + cq * 32 + u * 8);
#pragma unroll
        for (int j = 0; j < 8; j++) acc[u * 8 + j] += a * (float)w[j];
      }
    }
  }
  __syncthreads();
#pragma unroll
  for (int i = 0; i < 32; i++) cwl[sl * 136 + cq * 32 + i] = (f16)acc[i];
  __syncthreads();
#pragma unroll
  for (int i = 0; i < 4; i++) {
    int flat = i * 256 + t; int c = flat >> 3, ch = flat & 7;
    H8 o;
#pragma unroll
    for (int j = 0; j < 8; j++) o.h[j] = cwl[(ch * 8 + j) * 136 + c];
    *(half8*)(CWT + ((size_t)b * DH_N + c) * SL_N + s0 + ch * 8) = o.h;
  }
}

// ---------------------------------------------------------------------------
// flash kernel: S^T formulation, online softmax, PV vs precomputed CW^T.
// grid = 512 = (b, h, q-tile 128). 4 waves. s-tile 32. LDS 56 KB -> 2 blocks/CU.
// ---------------------------------------------------------------------------
#define KST 588   // k_lds row stride (halfs) -> 2-way-conflict b128 reads
#define CST 36
#define PST 36

__global__ __launch_bounds__(256, 2) void k_flash(
    const f16* __restrict__ Qeff, const f16* __restrict__ Cf,
    const f16* __restrict__ Krf, const f16* __restrict__ CWT,
    float* __restrict__ out) {
  __shared__ __align__(16) char smem[32 * KST * 2 + 128 * CST * 2 + 128 * PST * 2]; // 56064
  f16* k_lds   = (f16*)smem;                                    // [32][KST]
  f16* cwt_lds = (f16*)(smem + 32 * KST * 2);                   // [128][CST]
  f16* p_lds   = (f16*)(smem + 32 * KST * 2 + 128 * CST * 2);   // [128][PST] P^T [q][s]
  float* ot    = (float*)smem;                                  // epilogue [64][133]

  int t = threadIdx.x;
  int wave = t >> 6, lane = t & 63, l31 = lane & 31, lhi = lane >> 5;
  int qt = blockIdx.x & 7; int h = (blockIdx.x >> 3) & 31; int b = blockIdx.x >> 8;
  int kv = h >> 2;
  int qloc = wave * 32 + l31;

  // persistent Q fragments (B-operand): lane holds Q_eff[qbase+l31][kk*16+lhi*8 ..+7]
  half8 qf[36];
  {
    const f16* qrow = Qeff + ((size_t)(b * HQ_N + h) * QL_N + qt * 128 + qloc) * DEFF_N + lhi * 8;
#pragma unroll
    for (int kk = 0; kk < 36; kk++) qf[kk] = *(const half8*)(qrow + kk * 16);
  }

  floatx16 oacc[4];
#pragma unroll
  for (int ct = 0; ct < 4; ct++)
#pragma unroll
    for (int r = 0; r < 16; r++) oacc[ct][r] = 0.f;
  float m_run = -1e30f, l_run = 0.f;

  const f16* Cb = Cf + (size_t)b * SL_N * RANK_N;
  const f16* Kb = Krf + (size_t)(b * HKV_N + kv) * SL_N * ROPE_N;
  const f16* Wb = CWT + (size_t)b * DH_N * SL_N;

  for (int it = 0; it < 128; ++it) {
    int s0 = it * 32;
    __syncthreads();
    // ---- stage K_eff tile: C part (cols 0..511), 32 rows ----
#pragma unroll
    for (int i = 0; i < 8; i++) {
      int flat = i * 256 + t; int s = flat >> 6, ch = flat & 63;
      H8 v; v.h = *(const half8*)(Cb + (size_t)(s0 + s) * RANK_N + ch * 8);
      uint64_t* d = (uint64_t*)(k_lds + s * KST + ch * 8);
      d[0] = v.q[0]; d[1] = v.q[1];
    }
    // ---- rope part (cols 512..575) ----
    {
      int s = t >> 3, ch = t & 7;
      H8 v; v.h = *(const half8*)(Kb + (size_t)(s0 + s) * ROPE_N + ch * 8);
      uint64_t* d = (uint64_t*)(k_lds + s * KST + 512 + ch * 8);
      d[0] = v.q[0]; d[1] = v.q[1];
    }
    // ---- CW^T tile: 128 c x 32 s ----
#pragma unroll
    for (int i = 0; i < 2; i++) {
      int flat = i * 256 + t; int c = flat >> 2, ch = flat & 3;
      H8 v; v.h = *(const half8*)(Wb + (size_t)c * SL_N + s0 + ch * 8);
      uint64_t* d = (uint64_t*)(cwt_lds + c * CST + ch * 8);
      d[0] = v.q[0]; d[1] = v.q[1];
    }
    __syncthreads();

    // ---- S^T = K_eff(A) . Q^T(B) : 32 s rows x 32 q cols per wave ----
    floatx16 sa;
#pragma unroll
    for (int r = 0; r < 16; r++) sa[r] = 0.f;
    const f16* ka = k_lds + l31 * KST + lhi * 8;
#pragma unroll
    for (int kk = 0; kk < 36; kk++) {
      H8 a0;
      const uint64_t* p0 = (const uint64_t*)(ka + kk * 16);
      a0.q[0] = p0[0]; a0.q[1] = p0[1];
      sa = __builtin_amdgcn_mfma_f32_32x32x16_f16(a0.h, qf[kk], sa, 0, 0, 0);
    }

    // ---- online softmax: q in lane, s in regs (+ partner lane via xor32) ----
    float mt = -1e30f;
#pragma unroll
    for (int r = 0; r < 16; r++) mt = fmaxf(mt, sa[r]);
    mt = fmaxf(mt, __shfl_xor(mt, 32, 64));
    float m_new = fmaxf(m_run, mt);
    float alpha = __expf(m_run - m_new);
    float psum = 0.f;
#pragma unroll
    for (int r = 0; r < 16; r++) { sa[r] = __expf(sa[r] - m_new); psum += sa[r]; }
    psum += __shfl_xor(psum, 32, 64);
    l_run = l_run * alpha + psum;
    m_run = m_new;
#pragma unroll
    for (int ct = 0; ct < 4; ct++)
#pragma unroll
      for (int r = 0; r < 16; r++) oacc[ct][r] *= alpha;

    // ---- write P^T as [q][s] (each wave touches only its own q rows) ----
#pragma unroll
    for (int g = 0; g < 4; ++g) {
      H4 w;
      w.h[0] = (f16)sa[g * 4 + 0]; w.h[1] = (f16)sa[g * 4 + 1];
      w.h[2] = (f16)sa[g * 4 + 2]; w.h[3] = (f16)sa[g * 4 + 3];
      *(uint64_t*)(p_lds + qloc * PST + g * 8 + lhi * 4) = w.q;
    }

    // ---- PV: out^T = CW^T(A) . P^T(B), K = 32 s (2 ksteps) ----
#pragma unroll
    for (int ks = 0; ks < 2; ++ks) {
      H8 bf;
      const uint64_t* pb = (const uint64_t*)(p_lds + qloc * PST + ks * 16 + lhi * 8);
      bf.q[0] = pb[0]; bf.q[1] = pb[1];
#pragma unroll
      for (int ct = 0; ct < 4; ct++) {
        H8 af;
        const uint64_t* pa = (const uint64_t*)(cwt_lds + (ct * 32 + l31) * CST + ks * 16 + lhi * 8);
        af.q[0] = pa[0]; af.q[1] = pa[1];
        oacc[ct] = __builtin_amdgcn_mfma_f32_32x32x16_f16(af.h, bf.h, oacc[ct], 0, 0, 0);
      }
    }
  }

  // ---- epilogue: two q-halves through 34 KB LDS, coalesced fp32 stores ----
  float inv = 1.0f / l_run;
  float* outp = out + ((size_t)(b * HQ_N + h) * QL_N + qt * 128) * DH_N;
#pragma unroll
  for (int p = 0; p < 2; ++p) {
    __syncthreads();
    if ((qloc >> 6) == p) {
      int lr = qloc & 63;
#pragma unroll
      for (int ct = 0; ct < 4; ct++)
#pragma unroll
        for (int r = 0; r < 16; r++) {
          int c = ct * 32 + (r & 3) + 8 * (r >> 2) + 4 * lhi;
          ot[lr * 133 + c] = oacc[ct][r] * inv;
        }
    }
    __syncthreads();
#pragma unroll
    for (int i = 0; i < 8; i++) {
      int flat = i * 256 + t; int q = flat >> 5, ch = flat & 31;
      float4 v;
      v.x = ot[q * 133 + ch * 4 + 0];
      v.y = ot[q * 133 + ch * 4 + 1];
      v.z = ot[q * 133 + ch * 4 + 2];
      v.w = ot[q * 133 + ch * 4 + 3];
      *(float4*)(outp + (size_t)(p * 64 + q) * DH_N + ch * 4) = v;
    }
  }
}

// ---------------------------------------------------------------------------
extern "C" void kernel_launch(void* const* d_in, const int* in_sizes, int n_in,
                              void* d_out, int out_size, void* d_ws, size_t ws_size,
                              hipStream_t stream) {
  (void)in_sizes; (void)n_in; (void)out_size; (void)ws_size;
  const float* Q   = (const float*)d_in[0];
  const float* C   = (const float*)d_in[1];
  const float* Kr  = (const float*)d_in[2];
  const float* Ul  = (const float*)d_in[3];
  const float* WUK = (const float*)d_in[4];
  const float* WUV = (const float*)d_in[5];
  float* out = (float*)d_out;
  char* ws = (char*)d_ws;
  // workspace carve (~94.4 MB)
  f16* Qeff = (f16*)ws;                   // 75497472 B
  f16* Cf   = (f16*)(ws + 75497472);      //  8388608 B
  f16* Krf  = (f16*)(ws + 83886080);      //  8388608 B
  f16* CWT  = (f16*)(ws + 92274688);      //  2097152 B
  f16* M2T  = CWT;  // aliased: consumed by k_qeff, then overwritten by k_cw

  hipLaunchKernelGGL(k_convert, dim3(4096), dim3(256), 0, stream, C, Kr, Cf, Krf);
  hipLaunchKernelGGL(k_m2,      dim3(288),  dim3(256), 0, stream, Ul, WUK, M2T);
  hipLaunchKernelGGL(k_qeff,    dim3(1536), dim3(256), 0, stream, Q, M2T, Qeff);
  hipLaunchKernelGGL(k_cw,      dim3(128),  dim3(256), 0, stream, C, WUV, CWT);
  hipLaunchKernelGGL(k_flash,   dim3(512),  dim3(256), 0, stream, Qeff, Cf, Krf, CWT, out);
}

// Round 3
// 768.197 us; speedup vs baseline: 2.0693x; 1.2803x over previous
//
#include <hip/hip_runtime.h>
#include <stdint.h>

// ---- problem constants ----
#define B_N   2
#define HQ_N  32
#define HKV_N 8
#define QL_N  1024
#define SL_N  4096
#define DH_N  128
#define ROPE_N 64
#define RANK_N 512
#define DEFF_N 576   // RANK + ROPE

typedef _Float16 f16;
typedef _Float16 half8 __attribute__((ext_vector_type(8)));
typedef float floatx16 __attribute__((ext_vector_type(16)));

union H8 { half8 h; uint64_t q[2]; };
union H4 { f16 h[4]; uint64_t q; };

// ---------------------------------------------------------------------------
// prep 1: fp32 -> fp16 convert of C_kv_t2 and K_rope_t2
// ---------------------------------------------------------------------------
__global__ __launch_bounds__(256) void k_convert(const float* __restrict__ C,
                                                 const float* __restrict__ Kr,
                                                 f16* __restrict__ Cf,
                                                 f16* __restrict__ Krf) {
  const size_t NC = (size_t)B_N * SL_N * RANK_N;            // 4194304
  size_t idx = ((size_t)blockIdx.x * 256 + threadIdx.x) * 8; // covers 8388608
  const float* src;
  f16* dst;
  if (idx < NC) { src = C + idx;        dst = Cf + idx; }
  else          { src = Kr + (idx - NC); dst = Krf + (idx - NC); }
  float4 a = *(const float4*)(src);
  float4 b = *(const float4*)(src + 4);
  H8 o;
  o.h[0] = (f16)a.x; o.h[1] = (f16)a.y; o.h[2] = (f16)a.z; o.h[3] = (f16)a.w;
  o.h[4] = (f16)b.x; o.h[5] = (f16)b.y; o.h[6] = (f16)b.z; o.h[7] = (f16)b.w;
  *(half8*)dst = o.h;
}

// ---------------------------------------------------------------------------
// prep 2: M2T[c][d] (576 x 128, f16): Q_eff = Q @ M2.
// ---------------------------------------------------------------------------
__global__ __launch_bounds__(256) void k_m2(const float* __restrict__ Ul,
                                            const float* __restrict__ WUK,
                                            f16* __restrict__ M2T) {
  int idx = blockIdx.x * 256 + threadIdx.x;   // < 73728
  int c = idx >> 7, d = idx & 127;
  float v = 0.f;
  if (c < 512) {
    if (d >= 64) {
      int i = d - 64;
      for (int j = 0; j < 64; ++j) v += Ul[j * 64 + i] * WUK[j * 512 + c];
    }
  } else {
    if (d < 64) v = Ul[(c - 512) * 64 + d];
  }
  M2T[idx] = (f16)v;
}

// ---------------------------------------------------------------------------
// prep 3: Qeff = f16(Q) @ M2  via MFMA.  M=65536, K=128, N=576.
// grid = 1536 = 512 m-tiles(128) x 3 n-tiles(192). LDS-transpose epilogue.
// ---------------------------------------------------------------------------
#define OST 196
__global__ __launch_bounds__(256) void k_qeff(const float* __restrict__ Q,
                                              const f16* __restrict__ M2T,
                                              f16* __restrict__ Qeff) {
  __shared__ __align__(16) char qsm[128 * OST * 2];  // 50176 B (staging uses 33792)
  f16* qs = (f16*)qsm;   // [128][132] during MFMA
  int t = threadIdx.x;
  int wave = t >> 6, lane = t & 63, l31 = lane & 31, lhi = lane >> 5;
  int mb = blockIdx.x & 511, nb = blockIdx.x >> 9;
  size_t m0 = (size_t)mb * 128;
  int n0 = nb * 192;
  // stage Q tile (fp32 -> f16)
#pragma unroll
  for (int i = 0; i < 16; i++) {
    int flat = i * 256 + t; int row = flat >> 5, seg = flat & 31;
    float4 v = *(const float4*)(Q + (m0 + row) * DH_N + seg * 4);
    H4 o; o.h[0] = (f16)v.x; o.h[1] = (f16)v.y; o.h[2] = (f16)v.z; o.h[3] = (f16)v.w;
    *(uint64_t*)(qs + row * 132 + seg * 4) = o.q;
  }
  __syncthreads();
  floatx16 acc[6];
#pragma unroll
  for (int ct = 0; ct < 6; ct++)
#pragma unroll
    for (int r = 0; r < 16; r++) acc[ct][r] = 0.f;
#pragma unroll
  for (int kk = 0; kk < 8; ++kk) {
    H8 af;
    const uint64_t* pa = (const uint64_t*)(qs + (wave * 32 + l31) * 132 + kk * 16 + lhi * 8);
    af.q[0] = pa[0]; af.q[1] = pa[1];
#pragma unroll
    for (int ct = 0; ct < 6; ct++) {
      H8 bf; bf.h = *(const half8*)(M2T + (size_t)(n0 + ct * 32 + l31) * 128 + kk * 16 + lhi * 8);
      acc[ct] = __builtin_amdgcn_mfma_f32_32x32x16_f16(af.h, bf.h, acc[ct], 0, 0, 0);
    }
  }
  __syncthreads();
  f16* oq = (f16*)qsm;   // [128][OST]
#pragma unroll
  for (int ct = 0; ct < 6; ct++)
#pragma unroll
    for (int r = 0; r < 16; r++) {
      int row = (r & 3) + 8 * (r >> 2) + 4 * lhi;
      oq[(wave * 32 + row) * OST + ct * 32 + l31] = (f16)acc[ct][r];
    }
  __syncthreads();
  int q = t >> 1, hf = t & 1;
#pragma unroll
  for (int ct = 0; ct < 6; ct++) {
    const uint64_t* src = (const uint64_t*)(oq + q * OST + ct * 32 + hf * 16);
    uint64_t v0 = src[0], v1 = src[1], v2 = src[2], v3 = src[3];
    uint64_t* gd = (uint64_t*)(Qeff + (m0 + q) * DEFF_N + n0 + ct * 32 + hf * 16);
    gd[0] = v0; gd[1] = v1; gd[2] = v2; gd[3] = v3;
  }
}

// ---------------------------------------------------------------------------
// prep 4: CW^T[b][c][s] = (C[b] @ W_UV)^T   in fp16.   grid = 2*64 blocks.
// ---------------------------------------------------------------------------
__global__ __launch_bounds__(256) void k_cw(const float* __restrict__ C,
                                            const float* __restrict__ WUV,
                                            f16* __restrict__ CWT) {
  __shared__ f16 Wc[256 * 128];
  __shared__ f16 Cc[64 * 264];
  __shared__ f16 cwl[64 * 136];
  int t = threadIdx.x;
  int b = blockIdx.x >> 6, sc = blockIdx.x & 63;
  int s0 = sc * 64;
  int sl = t >> 2, cq = t & 3;
  float acc[32];
#pragma unroll
  for (int i = 0; i < 32; i++) acc[i] = 0.f;
  for (int rc = 0; rc < 2; ++rc) {
    __syncthreads();
    for (int i = 0; i < 128; i++) {
      int flat = i * 256 + t;
      Wc[flat] = (f16)WUV[(size_t)rc * 256 * 128 + flat];
    }
    for (int i = 0; i < 64; i++) {
      int flat = i * 256 + t; int s = flat >> 8, r = flat & 255;
      Cc[s * 264 + r] = (f16)C[((size_t)b * SL_N + s0 + s) * RANK_N + rc * 256 + r];
    }
    __syncthreads();
    for (int r = 0; r < 256; ++r) {
      float a = (float)Cc[sl * 264 + r];
#pragma unroll
      for (int u = 0; u < 4; u++) {
        half8 w = *(const half8*)(Wc + r * 128 + cq * 32 + u * 8);
#pragma unroll
        for (int j = 0; j < 8; j++) acc[u * 8 + j] += a * (float)w[j];
      }
    }
  }
  __syncthreads();
#pragma unroll
  for (int i = 0; i < 32; i++) cwl[sl * 136 + cq * 32 + i] = (f16)acc[i];
  __syncthreads();
#pragma unroll
  for (int i = 0; i < 4; i++) {
    int flat = i * 256 + t; int c = flat >> 3, ch = flat & 7;
    H8 o;
#pragma unroll
    for (int j = 0; j < 8; j++) o.h[j] = cwl[(ch * 8 + j) * 136 + c];
    *(half8*)(CWT + ((size_t)b * DH_N + c) * SL_N + s0 + ch * 8) = o.h;
  }
}

// ---------------------------------------------------------------------------
// flash kernel: S^T formulation, online softmax, PV vs precomputed CW^T.
// Double-buffered single-barrier pipeline; K-tile via global_load_lds DMA.
// grid = 512 = (b, h, q-tile 128). 4 waves. s-tile 32. 1 block/CU.
// ---------------------------------------------------------------------------
#define KROW 524   // halves; 1048 B row stride -> 2-way (free) b64 reads
#define RROW 68    // rope rows: 136 B stride -> 2-way
#define CROW 36
#define PROW 36

__global__ __launch_bounds__(256, 1) void k_flash(
    const f16* __restrict__ Qeff, const f16* __restrict__ Cf,
    const f16* __restrict__ Krf, const f16* __restrict__ CWT,
    float* __restrict__ out) {
  __shared__ __align__(16) char smem[103424];
  f16* kbuf0 = (f16*)smem;                    // [32][KROW]
  f16* kbuf1 = (f16*)(smem + 33536);
  f16* rbuf0 = (f16*)(smem + 67072);          // [32][RROW]
  f16* rbuf1 = (f16*)(smem + 71424);
  f16* cbuf0 = (f16*)(smem + 75776);          // [128][CROW]
  f16* cbuf1 = (f16*)(smem + 84992);
  f16* pb    = (f16*)(smem + 94208);          // [128][PROW]
  float* ot  = (float*)smem;                  // epilogue [64][133]

  int t = threadIdx.x;
  int wave = t >> 6, lane = t & 63, l31 = lane & 31, lhi = lane >> 5;
  int qt = blockIdx.x & 7; int h = (blockIdx.x >> 3) & 31; int b = blockIdx.x >> 8;
  int kv = h >> 2;
  int qloc = wave * 32 + l31;

  const f16* Cb = Cf + (size_t)b * SL_N * RANK_N;
  const f16* Kb = Krf + (size_t)(b * HKV_N + kv) * SL_N * ROPE_N;
  const f16* Wb = CWT + (size_t)b * DH_N * SL_N;

  // persistent Q fragments (B-operand): lane holds Q_eff[qbase+l31][kk*16+lhi*8 ..+7]
  half8 qf[36];
  {
    const f16* qrow = Qeff + ((size_t)(b * HQ_N + h) * QL_N + qt * 128 + qloc) * DEFF_N + lhi * 8;
#pragma unroll
    for (int kk = 0; kk < 36; kk++) qf[kk] = *(const half8*)(qrow + kk * 16);
  }

  floatx16 oacc[4];
#pragma unroll
  for (int ct = 0; ct < 4; ct++)
#pragma unroll
    for (int r = 0; r < 16; r++) oacc[ct][r] = 0.f;
  float m_run = -1e30f, l_run = 0.f;

  int rs = t >> 3, rch = t & 7;        // rope staging coords
  int cA = t >> 2, cch = t & 3;        // cwt staging coords (i=0)
  int cB = (256 + t) >> 2;             // cwt staging coords (i=1)

  // ---- preload tile 0 ----
  {
#pragma unroll
    for (int i = 0; i < 8; i++) {
      int s = i * 4 + wave;
      __builtin_amdgcn_global_load_lds(
          (const __attribute__((address_space(1))) void*)(Cb + (size_t)s * RANK_N + lane * 8),
          (__attribute__((address_space(3))) void*)(kbuf0 + s * KROW), 16, 0, 0);
    }
    H8 rp, c0, c1;
    rp.h = *(const half8*)(Kb + (size_t)rs * ROPE_N + rch * 8);
    c0.h = *(const half8*)(Wb + (size_t)cA * SL_N + cch * 8);
    c1.h = *(const half8*)(Wb + (size_t)cB * SL_N + cch * 8);
    uint64_t* d = (uint64_t*)(rbuf0 + rs * RROW + rch * 8);
    d[0] = rp.q[0]; d[1] = rp.q[1];
    uint64_t* e0 = (uint64_t*)(cbuf0 + cA * CROW + cch * 8);
    e0[0] = c0.q[0]; e0[1] = c0.q[1];
    uint64_t* e1 = (uint64_t*)(cbuf0 + cB * CROW + cch * 8);
    e1[0] = c1.q[0]; e1[1] = c1.q[1];
  }
  __syncthreads();

  for (int it = 0; it < 128; ++it) {
    f16* kc = (it & 1) ? kbuf1 : kbuf0;
    f16* rc = (it & 1) ? rbuf1 : rbuf0;
    f16* cc = (it & 1) ? cbuf1 : cbuf0;
    f16* kn = (it & 1) ? kbuf0 : kbuf1;
    f16* rn = (it & 1) ? rbuf0 : rbuf1;
    f16* cn = (it & 1) ? cbuf0 : cbuf1;
    bool pre = (it + 1) < 128;
    H8 rp, c0, c1;
    if (pre) {
      int s0n = (it + 1) * 32;
#pragma unroll
      for (int i = 0; i < 8; i++) {
        int s = i * 4 + wave;
        __builtin_amdgcn_global_load_lds(
            (const __attribute__((address_space(1))) void*)(Cb + (size_t)(s0n + s) * RANK_N + lane * 8),
            (__attribute__((address_space(3))) void*)(kn + s * KROW), 16, 0, 0);
      }
      rp.h = *(const half8*)(Kb + (size_t)(s0n + rs) * ROPE_N + rch * 8);
      c0.h = *(const half8*)(Wb + (size_t)cA * SL_N + s0n + cch * 8);
      c1.h = *(const half8*)(Wb + (size_t)cB * SL_N + s0n + cch * 8);
    }

    // ---- S^T = K_eff(A) . Q^T(B) : 32 s rows x 32 q cols per wave ----
    floatx16 sa;
#pragma unroll
    for (int r = 0; r < 16; r++) sa[r] = 0.f;
    const f16* ka = kc + l31 * KROW + lhi * 8;
#pragma unroll
    for (int kk = 0; kk < 32; kk++) {
      H8 a0;
      const uint64_t* p0 = (const uint64_t*)(ka + kk * 16);
      a0.q[0] = p0[0]; a0.q[1] = p0[1];
      sa = __builtin_amdgcn_mfma_f32_32x32x16_f16(a0.h, qf[kk], sa, 0, 0, 0);
    }
    const f16* ra = rc + l31 * RROW + lhi * 8;
#pragma unroll
    for (int kk = 0; kk < 4; kk++) {
      H8 a0;
      const uint64_t* p0 = (const uint64_t*)(ra + kk * 16);
      a0.q[0] = p0[0]; a0.q[1] = p0[1];
      sa = __builtin_amdgcn_mfma_f32_32x32x16_f16(a0.h, qf[32 + kk], sa, 0, 0, 0);
    }

    // ---- online softmax: q in lane, s in regs (+ partner lane via xor32) ----
    float mt = -1e30f;
#pragma unroll
    for (int r = 0; r < 16; r++) mt = fmaxf(mt, sa[r]);
    mt = fmaxf(mt, __shfl_xor(mt, 32, 64));
    float m_new = fmaxf(m_run, mt);
    float alpha = __expf(m_run - m_new);
    float psum = 0.f;
#pragma unroll
    for (int r = 0; r < 16; r++) { sa[r] = __expf(sa[r] - m_new); psum += sa[r]; }
    psum += __shfl_xor(psum, 32, 64);
    l_run = l_run * alpha + psum;
    m_run = m_new;
#pragma unroll
    for (int ct = 0; ct < 4; ct++)
#pragma unroll
      for (int r = 0; r < 16; r++) oacc[ct][r] *= alpha;

    // ---- write P^T as [q][s] (wave-private rows) ----
#pragma unroll
    for (int g = 0; g < 4; ++g) {
      H4 w;
      w.h[0] = (f16)sa[g * 4 + 0]; w.h[1] = (f16)sa[g * 4 + 1];
      w.h[2] = (f16)sa[g * 4 + 2]; w.h[3] = (f16)sa[g * 4 + 3];
      *(uint64_t*)(pb + qloc * PROW + g * 8 + lhi * 4) = w.q;
    }

    // ---- PV: out^T = CW^T(A) . P^T(B), K = 32 s (2 ksteps) ----
#pragma unroll
    for (int ks = 0; ks < 2; ++ks) {
      H8 bf;
      const uint64_t* pv = (const uint64_t*)(pb + qloc * PROW + ks * 16 + lhi * 8);
      bf.q[0] = pv[0]; bf.q[1] = pv[1];
#pragma unroll
      for (int ct = 0; ct < 4; ct++) {
        H8 af;
        const uint64_t* pa = (const uint64_t*)(cc + (ct * 32 + l31) * CROW + ks * 16 + lhi * 8);
        af.q[0] = pa[0]; af.q[1] = pa[1];
        oacc[ct] = __builtin_amdgcn_mfma_f32_32x32x16_f16(af.h, bf.h, oacc[ct], 0, 0, 0);
      }
    }

    // ---- commit rope/cwt prefetch for tile it+1 ----
    if (pre) {
      uint64_t* d = (uint64_t*)(rn + rs * RROW + rch * 8);
      d[0] = rp.q[0]; d[1] = rp.q[1];
      uint64_t* e0 = (uint64_t*)(cn + cA * CROW + cch * 8);
      e0[0] = c0.q[0]; e0[1] = c0.q[1];
      uint64_t* e1 = (uint64_t*)(cn + cB * CROW + cch * 8);
      e1[0] = c1.q[0]; e1[1] = c1.q[1];
    }
    __syncthreads();
  }

  // ---- epilogue: two q-halves through LDS, coalesced fp32 stores ----
  float inv = 1.0f / l_run;
  float* outp = out + ((size_t)(b * HQ_N + h) * QL_N + qt * 128) * DH_N;
#pragma unroll
  for (int p = 0; p < 2; ++p) {
    __syncthreads();
    if ((qloc >> 6) == p) {
      int lr = qloc & 63;
#pragma unroll
      for (int ct = 0; ct < 4; ct++)
#pragma unroll
        for (int r = 0; r < 16; r++) {
          int c = ct * 32 + (r & 3) + 8 * (r >> 2) + 4 * lhi;
          ot[lr * 133 + c] = oacc[ct][r] * inv;
        }
    }
    __syncthreads();
#pragma unroll
    for (int i = 0; i < 8; i++) {
      int flat = i * 256 + t; int q = flat >> 5, ch = flat & 31;
      float4 v;
      v.x = ot[q * 133 + ch * 4 + 0];
      v.y = ot[q * 133 + ch * 4 + 1];
      v.z = ot[q * 133 + ch * 4 + 2];
      v.w = ot[q * 133 + ch * 4 + 3];
      *(float4*)(outp + (size_t)(p * 64 + q) * DH_N + ch * 4) = v;
    }
  }
}

// ---------------------------------------------------------------------------
extern "C" void kernel_launch(void* const* d_in, const int* in_sizes, int n_in,
                              void* d_out, int out_size, void* d_ws, size_t ws_size,
                              hipStream_t stream) {
  (void)in_sizes; (void)n_in; (void)out_size; (void)ws_size;
  const float* Q   = (const float*)d_in[0];
  const float* C   = (const float*)d_in[1];
  const float* Kr  = (const float*)d_in[2];
  const float* Ul  = (const float*)d_in[3];
  const float* WUK = (const float*)d_in[4];
  const float* WUV = (const float*)d_in[5];
  float* out = (float*)d_out;
  char* ws = (char*)d_ws;
  // workspace carve (~94.4 MB)
  f16* Qeff = (f16*)ws;                   // 75497472 B
  f16* Cf   = (f16*)(ws + 75497472);      //  8388608 B
  f16* Krf  = (f16*)(ws + 83886080);      //  8388608 B
  f16* CWT  = (f16*)(ws + 92274688);      //  2097152 B
  f16* M2T  = CWT;  // aliased: consumed by k_qeff, then overwritten by k_cw

  hipLaunchKernelGGL(k_convert, dim3(4096), dim3(256), 0, stream, C, Kr, Cf, Krf);
  hipLaunchKernelGGL(k_m2,      dim3(288),  dim3(256), 0, stream, Ul, WUK, M2T);
  hipLaunchKernelGGL(k_qeff,    dim3(1536), dim3(256), 0, stream, Q, M2T, Qeff);
  hipLaunchKernelGGL(k_cw,      dim3(128),  dim3(256), 0, stream, C, WUV, CWT);
  hipLaunchKernelGGL(k_flash,   dim3(512),  dim3(256), 0, stream, Qeff, Cf, Krf, CWT, out);
}

// Round 7
// 666.498 us; speedup vs baseline: 2.3851x; 1.1526x over previous
//
#include <hip/hip_runtime.h>
#include <stdint.h>

// ---- problem constants ----
#define B_N   2
#define HQ_N  32
#define HKV_N 8
#define QL_N  1024
#define SL_N  4096
#define DH_N  128
#define ROPE_N 64
#define RANK_N 512
#define DEFF_N 576   // RANK + ROPE

typedef _Float16 f16;
typedef _Float16 half8 __attribute__((ext_vector_type(8)));
typedef float floatx16 __attribute__((ext_vector_type(16)));

union H8 { half8 h; uint64_t q[2]; };
union H4 { f16 h[4]; uint64_t q; };

// ---------------------------------------------------------------------------
// prep 1: fp32 -> fp16 convert of C_kv_t2 and K_rope_t2
// ---------------------------------------------------------------------------
__global__ __launch_bounds__(256) void k_convert(const float* __restrict__ C,
                                                 const float* __restrict__ Kr,
                                                 f16* __restrict__ Cf,
                                                 f16* __restrict__ Krf) {
  const size_t NC = (size_t)B_N * SL_N * RANK_N;            // 4194304
  size_t idx = ((size_t)blockIdx.x * 256 + threadIdx.x) * 8; // covers 8388608
  const float* src;
  f16* dst;
  if (idx < NC) { src = C + idx;        dst = Cf + idx; }
  else          { src = Kr + (idx - NC); dst = Krf + (idx - NC); }
  float4 a = *(const float4*)(src);
  float4 b = *(const float4*)(src + 4);
  H8 o;
  o.h[0] = (f16)a.x; o.h[1] = (f16)a.y; o.h[2] = (f16)a.z; o.h[3] = (f16)a.w;
  o.h[4] = (f16)b.x; o.h[5] = (f16)b.y; o.h[6] = (f16)b.z; o.h[7] = (f16)b.w;
  *(half8*)dst = o.h;
}

// ---------------------------------------------------------------------------
// prep 2: M2T[c][d] (576 x 128, f16): Q_eff = Q @ M2.
// ---------------------------------------------------------------------------
__global__ __launch_bounds__(256) void k_m2(const float* __restrict__ Ul,
                                            const float* __restrict__ WUK,
                                            f16* __restrict__ M2T) {
  int idx = blockIdx.x * 256 + threadIdx.x;   // < 73728
  int c = idx >> 7, d = idx & 127;
  float v = 0.f;
  if (c < 512) {
    if (d >= 64) {
      int i = d - 64;
      for (int j = 0; j < 64; ++j) v += Ul[j * 64 + i] * WUK[j * 512 + c];
    }
  } else {
    if (d < 64) v = Ul[(c - 512) * 64 + d];
  }
  M2T[idx] = (f16)v;
}

// ---------------------------------------------------------------------------
// prep 3: Qeff = f16(Q) @ M2  via MFMA.  M=65536, K=128, N=576.
// grid = 1536 = 512 m-tiles(128) x 3 n-tiles(192). LDS-transpose epilogue.
// ---------------------------------------------------------------------------
#define OST 196
__global__ __launch_bounds__(256) void k_qeff(const float* __restrict__ Q,
                                              const f16* __restrict__ M2T,
                                              f16* __restrict__ Qeff) {
  __shared__ __align__(16) char qsm[128 * OST * 2];  // 50176 B (staging uses 33792)
  f16* qs = (f16*)qsm;   // [128][132] during MFMA
  int t = threadIdx.x;
  int wave = t >> 6, lane = t & 63, l31 = lane & 31, lhi = lane >> 5;
  int mb = blockIdx.x & 511, nb = blockIdx.x >> 9;
  size_t m0 = (size_t)mb * 128;
  int n0 = nb * 192;
  // stage Q tile (fp32 -> f16)
#pragma unroll
  for (int i = 0; i < 16; i++) {
    int flat = i * 256 + t; int row = flat >> 5, seg = flat & 31;
    float4 v = *(const float4*)(Q + (m0 + row) * DH_N + seg * 4);
    H4 o; o.h[0] = (f16)v.x; o.h[1] = (f16)v.y; o.h[2] = (f16)v.z; o.h[3] = (f16)v.w;
    *(uint64_t*)(qs + row * 132 + seg * 4) = o.q;
  }
  __syncthreads();
  floatx16 acc[6];
#pragma unroll
  for (int ct = 0; ct < 6; ct++)
#pragma unroll
    for (int r = 0; r < 16; r++) acc[ct][r] = 0.f;
#pragma unroll
  for (int kk = 0; kk < 8; ++kk) {
    H8 af;
    const uint64_t* pa = (const uint64_t*)(qs + (wave * 32 + l31) * 132 + kk * 16 + lhi * 8);
    af.q[0] = pa[0]; af.q[1] = pa[1];
#pragma unroll
    for (int ct = 0; ct < 6; ct++) {
      H8 bf; bf.h = *(const half8*)(M2T + (size_t)(n0 + ct * 32 + l31) * 128 + kk * 16 + lhi * 8);
      acc[ct] = __builtin_amdgcn_mfma_f32_32x32x16_f16(af.h, bf.h, acc[ct], 0, 0, 0);
    }
  }
  __syncthreads();
  f16* oq = (f16*)qsm;   // [128][OST]
#pragma unroll
  for (int ct = 0; ct < 6; ct++)
#pragma unroll
    for (int r = 0; r < 16; r++) {
      int row = (r & 3) + 8 * (r >> 2) + 4 * lhi;
      oq[(wave * 32 + row) * OST + ct * 32 + l31] = (f16)acc[ct][r];
    }
  __syncthreads();
  int q = t >> 1, hf = t & 1;
#pragma unroll
  for (int ct = 0; ct < 6; ct++) {
    const uint64_t* src = (const uint64_t*)(oq + q * OST + ct * 32 + hf * 16);
    uint64_t v0 = src[0], v1 = src[1], v2 = src[2], v3 = src[3];
    uint64_t* gd = (uint64_t*)(Qeff + (m0 + q) * DEFF_N + n0 + ct * 32 + hf * 16);
    gd[0] = v0; gd[1] = v1; gd[2] = v2; gd[3] = v3;
  }
}

// ---------------------------------------------------------------------------
// prep 4: CW^T[b][c][s] = (C[b] @ W_UV)^T   in fp16.   grid = 2*64 blocks.
// ---------------------------------------------------------------------------
__global__ __launch_bounds__(256) void k_cw(const float* __restrict__ C,
                                            const float* __restrict__ WUV,
                                            f16* __restrict__ CWT) {
  __shared__ f16 Wc[256 * 128];
  __shared__ f16 Cc[64 * 264];
  __shared__ f16 cwl[64 * 136];
  int t = threadIdx.x;
  int b = blockIdx.x >> 6, sc = blockIdx.x & 63;
  int s0 = sc * 64;
  int sl = t >> 2, cq = t & 3;
  float acc[32];
#pragma unroll
  for (int i = 0; i < 32; i++) acc[i] = 0.f;
  for (int rc = 0; rc < 2; ++rc) {
    __syncthreads();
    for (int i = 0; i < 128; i++) {
      int flat = i * 256 + t;
      Wc[flat] = (f16)WUV[(size_t)rc * 256 * 128 + flat];
    }
    for (int i = 0; i < 64; i++) {
      int flat = i * 256 + t; int s = flat >> 8, r = flat & 255;
      Cc[s * 264 + r] = (f16)C[((size_t)b * SL_N + s0 + s) * RANK_N + rc * 256 + r];
    }
    __syncthreads();
    for (int r = 0; r < 256; ++r) {
      float a = (float)Cc[sl * 264 + r];
#pragma unroll
      for (int u = 0; u < 4; u++) {
        half8 w = *(const half8*)(Wc + r * 128 + cq * 32 + u * 8);
#pragma unroll
        for (int j = 0; j < 8; j++) acc[u * 8 + j] += a * (float)w[j];
      }
    }
  }
  __syncthreads();
#pragma unroll
  for (int i = 0; i < 32; i++) cwl[sl * 136 + cq * 32 + i] = (f16)acc[i];
  __syncthreads();
#pragma unroll
  for (int i = 0; i < 4; i++) {
    int flat = i * 256 + t; int c = flat >> 3, ch = flat & 7;
    H8 o;
#pragma unroll
    for (int j = 0; j < 8; j++) o.h[j] = cwl[(ch * 8 + j) * 136 + c];
    *(half8*)(CWT + ((size_t)b * DH_N + c) * SL_N + s0 + ch * 8) = o.h;
  }
}

// ---------------------------------------------------------------------------
// flash kernel: S^T formulation, online softmax, PV vs precomputed CW^T.
// 256 threads / 4 waves, s-tile 32, SINGLE kbuf (rope merged, KROW=580),
// 2-barrier pipelined loop: S^T -> barrier -> DMA(i+1)+commits -> softmax+PV
// (covers DMA flight) -> barrier.  LDS 63 KB -> 2 blocks/CU.
// grid = 512 = (b, h, q-tile 128).
// ---------------------------------------------------------------------------
#define KROW 580   // halves; 1160 B stride = 290 dw = 2 mod 32 -> 2-way (free)
#define CROW 36
#define PROW 36

__global__ __launch_bounds__(256, 2) void k_flash(
    const f16* __restrict__ Qeff, const f16* __restrict__ Cf,
    const f16* __restrict__ Krf, const f16* __restrict__ CWT,
    float* __restrict__ out) {
  __shared__ __align__(16) char smem[64768];
  f16* kbuf  = (f16*)smem;                    // [32][KROW] 37120 B (cols 512..575 = rope)
  f16* cbuf0 = (f16*)(smem + 37120);          // [128][CROW] 9216 B
  f16* cbuf1 = (f16*)(smem + 46336);
  f16* pb    = (f16*)(smem + 55552);          // [128][PROW] 9216 B
  float* ot  = (float*)smem;                  // epilogue [64][133] 34048 B

  int t = threadIdx.x;
  int wave = t >> 6, lane = t & 63, l31 = lane & 31, lhi = lane >> 5;
  int qt = blockIdx.x & 7; int h = (blockIdx.x >> 3) & 31; int b = blockIdx.x >> 8;
  int kv = h >> 2;
  int qloc = wave * 32 + l31;

  const f16* Cb = Cf + (size_t)b * SL_N * RANK_N;
  const f16* Kb = Krf + (size_t)(b * HKV_N + kv) * SL_N * ROPE_N;
  const f16* Wb = CWT + (size_t)b * DH_N * SL_N;

  // persistent Q fragments (B-operand): lane holds Q_eff[qbase+qloc][kk*16+lhi*8 ..+7]
  half8 qf[36];
  {
    const f16* qrow = Qeff + ((size_t)(b * HQ_N + h) * QL_N + qt * 128 + qloc) * DEFF_N + lhi * 8;
#pragma unroll
    for (int kk = 0; kk < 36; kk++) qf[kk] = *(const half8*)(qrow + kk * 16);
  }

  floatx16 oacc[4];
#pragma unroll
  for (int ct = 0; ct < 4; ct++)
#pragma unroll
    for (int r = 0; r < 16; r++) oacc[ct][r] = 0.f;
  float m_run = -1e30f, l_run = 0.f;

  int rs = t >> 3, rch = t & 7;   // rope staging: row rs, col 512 + rch*8
  int cA = t >> 2, cch = t & 3;   // cwt staging: rows cA and 64+cA, cols cch*8

  // ---- preload tile 0 ----
  {
#pragma unroll
    for (int i = 0; i < 8; i++) {
      int s = i * 4 + wave;
      __builtin_amdgcn_global_load_lds(
          (const __attribute__((address_space(1))) void*)(Cb + (size_t)s * RANK_N + lane * 8),
          (__attribute__((address_space(3))) void*)(kbuf + s * KROW), 16, 0, 0);
    }
    H8 rp, c0, c1;
    rp.h = *(const half8*)(Kb + (size_t)rs * ROPE_N + rch * 8);
    c0.h = *(const half8*)(Wb + (size_t)cA * SL_N + cch * 8);
    c1.h = *(const half8*)(Wb + (size_t)(64 + cA) * SL_N + cch * 8);
    uint64_t* d = (uint64_t*)(kbuf + rs * KROW + 512 + rch * 8);
    d[0] = rp.q[0]; d[1] = rp.q[1];
    uint64_t* e0 = (uint64_t*)(cbuf0 + cA * CROW + cch * 8);
    e0[0] = c0.q[0]; e0[1] = c0.q[1];
    uint64_t* e1 = (uint64_t*)(cbuf0 + (64 + cA) * CROW + cch * 8);
    e1[0] = c1.q[0]; e1[1] = c1.q[1];
  }
  __syncthreads();

  for (int it = 0; it < 128; ++it) {
    f16* cc = (it & 1) ? cbuf1 : cbuf0;
    f16* cn = (it & 1) ? cbuf0 : cbuf1;
    bool pre = (it + 1) < 128;
    int s0n = (it + 1) * 32;
    H8 rp, c0, c1;
    if (pre) {  // register prefetch (in flight during S^T)
      rp.h = *(const half8*)(Kb + (size_t)(s0n + rs) * ROPE_N + rch * 8);
      c0.h = *(const half8*)(Wb + (size_t)cA * SL_N + s0n + cch * 8);
      c1.h = *(const half8*)(Wb + (size_t)(64 + cA) * SL_N + s0n + cch * 8);
    }

    // ---- S^T = K_eff(A) . Q^T(B) : only phase reading kbuf ----
    floatx16 sa;
#pragma unroll
    for (int r = 0; r < 16; r++) sa[r] = 0.f;
    const f16* ka = kbuf + l31 * KROW + lhi * 8;
#pragma unroll
    for (int kk = 0; kk < 36; kk++) {
      H8 a0;
      const uint64_t* p0 = (const uint64_t*)(ka + kk * 16);
      a0.q[0] = p0[0]; a0.q[1] = p0[1];
      sa = __builtin_amdgcn_mfma_f32_32x32x16_f16(a0.h, qf[kk], sa, 0, 0, 0);
    }
    __syncthreads();   // barrier A: kbuf free; prefetch regs landed

    // ---- issue DMA for tile i+1 + commit reg prefetches (flight covered below) ----
    if (pre) {
#pragma unroll
      for (int i = 0; i < 8; i++) {
        int s = i * 4 + wave;
        __builtin_amdgcn_global_load_lds(
            (const __attribute__((address_space(1))) void*)(Cb + (size_t)(s0n + s) * RANK_N + lane * 8),
            (__attribute__((address_space(3))) void*)(kbuf + s * KROW), 16, 0, 0);
      }
      uint64_t* d = (uint64_t*)(kbuf + rs * KROW + 512 + rch * 8);
      d[0] = rp.q[0]; d[1] = rp.q[1];
      uint64_t* e0 = (uint64_t*)(cn + cA * CROW + cch * 8);
      e0[0] = c0.q[0]; e0[1] = c0.q[1];
      uint64_t* e1 = (uint64_t*)(cn + (64 + cA) * CROW + cch * 8);
      e1[0] = c1.q[0]; e1[1] = c1.q[1];
    }

    // ---- online softmax: q in lane, s in regs (+ partner lane via xor32) ----
    float mt = -1e30f;
#pragma unroll
    for (int r = 0; r < 16; r++) mt = fmaxf(mt, sa[r]);
    mt = fmaxf(mt, __shfl_xor(mt, 32, 64));
    float m_new = fmaxf(m_run, mt);
    float alpha = __expf(m_run - m_new);
    float psum = 0.f;
#pragma unroll
    for (int r = 0; r < 16; r++) { sa[r] = __expf(sa[r] - m_new); psum += sa[r]; }
    psum += __shfl_xor(psum, 32, 64);
    l_run = l_run * alpha + psum;
    m_run = m_new;
#pragma unroll
    for (int ct = 0; ct < 4; ct++)
#pragma unroll
      for (int r = 0; r < 16; r++) oacc[ct][r] *= alpha;

    // ---- write P^T as [q][s] (wave-private rows) ----
#pragma unroll
    for (int g = 0; g < 4; ++g) {
      H4 w;
      w.h[0] = (f16)sa[g * 4 + 0]; w.h[1] = (f16)sa[g * 4 + 1];
      w.h[2] = (f16)sa[g * 4 + 2]; w.h[3] = (f16)sa[g * 4 + 3];
      *(uint64_t*)(pb + qloc * PROW + g * 8 + lhi * 4) = w.q;
    }

    // ---- PV: out^T = CW^T(A) . P^T(B), K = 32 s (2 ksteps) ----
#pragma unroll
    for (int ks = 0; ks < 2; ++ks) {
      H8 bf;
      const uint64_t* pv = (const uint64_t*)(pb + qloc * PROW + ks * 16 + lhi * 8);
      bf.q[0] = pv[0]; bf.q[1] = pv[1];
#pragma unroll
      for (int ct = 0; ct < 4; ct++) {
        H8 af;
        const uint64_t* pa = (const uint64_t*)(cc + (ct * 32 + l31) * CROW + ks * 16 + lhi * 8);
        af.q[0] = pa[0]; af.q[1] = pa[1];
        oacc[ct] = __builtin_amdgcn_mfma_f32_32x32x16_f16(af.h, bf.h, oacc[ct], 0, 0, 0);
      }
    }
    __syncthreads();   // barrier B: DMA + LDS commits visible for next S^T
  }

  // ---- epilogue: two q-halves through LDS, coalesced fp32 stores ----
  float inv = 1.0f / l_run;
  float* outp = out + ((size_t)(b * HQ_N + h) * QL_N + qt * 128) * DH_N;
#pragma unroll
  for (int p = 0; p < 2; ++p) {
    __syncthreads();
    if ((qloc >> 6) == p) {
      int lr = qloc & 63;
#pragma unroll
      for (int ct = 0; ct < 4; ct++)
#pragma unroll
        for (int r = 0; r < 16; r++) {
          int c = ct * 32 + (r & 3) + 8 * (r >> 2) + 4 * lhi;
          ot[lr * 133 + c] = oacc[ct][r] * inv;
        }
    }
    __syncthreads();
#pragma unroll
    for (int i = 0; i < 8; i++) {
      int flat = i * 256 + t; int q = flat >> 5, ch = flat & 31;
      float4 v;
      v.x = ot[q * 133 + ch * 4 + 0];
      v.y = ot[q * 133 + ch * 4 + 1];
      v.z = ot[q * 133 + ch * 4 + 2];
      v.w = ot[q * 133 + ch * 4 + 3];
      *(float4*)(outp + (size_t)(p * 64 + q) * DH_N + ch * 4) = v;
    }
  }
}

// ---------------------------------------------------------------------------
extern "C" void kernel_launch(void* const* d_in, const int* in_sizes, int n_in,
                              void* d_out, int out_size, void* d_ws, size_t ws_size,
                              hipStream_t stream) {
  (void)in_sizes; (void)n_in; (void)out_size; (void)ws_size;
  const float* Q   = (const float*)d_in[0];
  const float* C   = (const float*)d_in[1];
  const float* Kr  = (const float*)d_in[2];
  const float* Ul  = (const float*)d_in[3];
  const float* WUK = (const float*)d_in[4];
  const float* WUV = (const float*)d_in[5];
  float* out = (float*)d_out;
  char* ws = (char*)d_ws;
  // workspace carve (~94.4 MB)
  f16* Qeff = (f16*)ws;                   // 75497472 B
  f16* Cf   = (f16*)(ws + 75497472);      //  8388608 B
  f16* Krf  = (f16*)(ws + 83886080);      //  8388608 B
  f16* CWT  = (f16*)(ws + 92274688);      //  2097152 B
  f16* M2T  = CWT;  // aliased: consumed by k_qeff, then overwritten by k_cw

  hipLaunchKernelGGL(k_convert, dim3(4096), dim3(256), 0, stream, C, Kr, Cf, Krf);
  hipLaunchKernelGGL(k_m2,      dim3(288),  dim3(256), 0, stream, Ul, WUK, M2T);
  hipLaunchKernelGGL(k_qeff,    dim3(1536), dim3(256), 0, stream, Q, M2T, Qeff);
  hipLaunchKernelGGL(k_cw,      dim3(128),  dim3(256), 0, stream, C, WUV, CWT);
  hipLaunchKernelGGL(k_flash,   dim3(512),  dim3(256), 0, stream, Qeff, Cf, Krf, CWT, out);
}